// Round 13
// baseline (487.627 us; speedup 1.0000x reference)
//
#include <hip/hip_runtime.h>
#include <math.h>

#define N_NODESC    20000
#define N_EDGES_RAW 320000
#define N_EDGES_TOT 340000   // + self-loops
#define IN_CHC      4
#define HIDC        64
#define HEADSC      4
#define NUM_GRAPHSC 64
#define NEG_SLOPEF  0.2f

// ---- monotonic float<->uint mapping for atomic max (handles negatives) ----
__device__ __forceinline__ unsigned fmap(float f) {
    unsigned u = __float_as_uint(f);
    return (u & 0x80000000u) ? ~u : (u | 0x80000000u);
}
__device__ __forceinline__ float funmap(unsigned u) {
    u = (u & 0x80000000u) ? (u ^ 0x80000000u) : ~u;
    return __uint_as_float(u);
}

__device__ __forceinline__ void edge_sd(int e, const int* __restrict__ ei, int& s, int& d) {
    if (e < N_EDGES_RAW) { s = ei[e]; d = ei[N_EDGES_RAW + e]; }
    else                 { s = d = e - N_EDGES_RAW; }
}

// ================= CSR build (by destination) =================
__global__ void k_hist(const int* __restrict__ ei, int* __restrict__ deg) {
    int e = blockIdx.x * blockDim.x + threadIdx.x;
    if (e >= N_EDGES_TOT) return;
    int s, d; edge_sd(e, ei, s, d);
    atomicAdd(&deg[d], 1);
}

// single block, 1024 threads, 20 elems/thread: exclusive scan of deg -> rowptr, cursor
__global__ void k_scan(const int* __restrict__ deg, int* __restrict__ rowptr,
                       int* __restrict__ cursor) {
    const int PER = 20;
    int t = threadIdx.x;           // 0..1023
    int base = t * PER;
    int local[PER];
    int s = 0;
#pragma unroll
    for (int i = 0; i < PER; ++i) {
        int idx = base + i;
        int v = (idx < N_NODESC) ? deg[idx] : 0;
        local[i] = s; s += v;
    }
    int lane = t & 63, wid = t >> 6;
    int inc = s;
    for (int off = 1; off < 64; off <<= 1) {
        int u = __shfl_up(inc, off);
        if (lane >= off) inc += u;
    }
    __shared__ int wsum[16], woff[16];
    if (lane == 63) wsum[wid] = inc;
    __syncthreads();
    if (t == 0) { int a = 0; for (int w = 0; w < 16; ++w) { woff[w] = a; a += wsum[w]; } }
    __syncthreads();
    int thread_excl = inc - s + woff[wid];
#pragma unroll
    for (int i = 0; i < PER; ++i) {
        int idx = base + i;
        if (idx < N_NODESC) {
            int v = thread_excl + local[i];
            rowptr[idx] = v; cursor[idx] = v;
        }
    }
    if (t == 1023) rowptr[N_NODESC] = thread_excl + s;
}

__global__ void k_scatter(const int* __restrict__ ei, int* __restrict__ cursor,
                          int* __restrict__ esrc, int* __restrict__ eidx) {
    int e = blockIdx.x * blockDim.x + threadIdx.x;
    if (e >= N_EDGES_TOT) return;
    int s, d; edge_sd(e, ei, s, d);
    int pos = atomicAdd(&cursor[d], 1);
    esrc[pos] = s;
    eidx[pos] = e;
}

// ================= layer 1 =================
// grid = N_NODES blocks, 256 threads. h1[n][256], as1/ad1[n][4]
__global__ void k_proj1(const float* __restrict__ x, const float* __restrict__ W1,
                        const float* __restrict__ a_src, const float* __restrict__ a_dst,
                        float* __restrict__ h1, float* __restrict__ as1, float* __restrict__ ad1) {
    int n = blockIdx.x;
    int t = threadIdx.x;                 // 0..255 ; head = t>>6, c = t&63
    __shared__ float xs[IN_CHC];
    if (t < IN_CHC) xs[t] = x[n * IN_CHC + t];
    __syncthreads();
    float h = xs[0] * W1[t] + xs[1] * W1[256 + t] + xs[2] * W1[512 + t] + xs[3] * W1[768 + t];
    h1[n * 256 + t] = h;
    float ps = h * a_src[t];
    float pd = h * a_dst[t];
    for (int off = 32; off > 0; off >>= 1) {   // 64-lane wave == one head
        ps += __shfl_down(ps, off);
        pd += __shfl_down(pd, off);
    }
    if ((t & 63) == 0) {
        int head = t >> 6;
        as1[n * HEADSC + head] = ps;
        ad1[n * HEADSC + head] = pd;
    }
}

__global__ void k_edge1(const int* __restrict__ ei, const float* __restrict__ as1,
                        const float* __restrict__ ad1, float* __restrict__ e1,
                        unsigned* __restrict__ m1) {
    int idx = blockIdx.x * blockDim.x + threadIdx.x;
    if (idx >= N_EDGES_TOT * HEADSC) return;
    int e = idx >> 2, hd = idx & 3;
    int s, d; edge_sd(e, ei, s, d);
    float sc = as1[s * HEADSC + hd] + ad1[d * HEADSC + hd];
    sc = sc > 0.f ? sc : NEG_SLOPEF * sc;
    e1[idx] = sc;
    atomicMax(&m1[d * HEADSC + hd], fmap(sc));
}

__global__ void k_exp1(const int* __restrict__ ei, float* __restrict__ e1,
                       const unsigned* __restrict__ m1, float* __restrict__ denom1) {
    int idx = blockIdx.x * blockDim.x + threadIdx.x;
    if (idx >= N_EDGES_TOT * HEADSC) return;
    int e = idx >> 2, hd = idx & 3;
    int s, d; edge_sd(e, ei, s, d);
    float ex = expf(e1[idx] - funmap(m1[d * HEADSC + hd]));
    e1[idx] = ex;
    atomicAdd(&denom1[d * HEADSC + hd], ex);
}

// CSR gather aggregation, one wave per dst, 4-edge unroll for MLP.
// Fused bias + ELU. grid = ceil(N/4) blocks x 256 threads (4 waves).
__global__ void k_aggr1(const int* __restrict__ rowptr, const int* __restrict__ esrc,
                        const int* __restrict__ eidx, const float* __restrict__ h1,
                        const float* __restrict__ e1, const float* __restrict__ denom1,
                        const float* __restrict__ b1, float* __restrict__ h1b) {
    int d = blockIdx.x * 4 + (threadIdx.x >> 6);
    if (d >= N_NODESC) return;
    int lane = threadIdx.x & 63;
    int beg = rowptr[d], end = rowptr[d + 1];
    float4 den = *(const float4*)&denom1[d * 4];
    float i0 = 1.f / den.x, i1 = 1.f / den.y, i2 = 1.f / den.z, i3 = 1.f / den.w;
    float a0 = 0.f, a1 = 0.f, a2 = 0.f, a3 = 0.f;
    int i = beg;
    for (; i + 4 <= end; i += 4) {
        int s0 = esrc[i], s1 = esrc[i + 1], s2 = esrc[i + 2], s3 = esrc[i + 3];
        int q0 = eidx[i], q1 = eidx[i + 1], q2 = eidx[i + 2], q3 = eidx[i + 3];
        float4 x0 = *(const float4*)&e1[q0 * 4];
        float4 x1 = *(const float4*)&e1[q1 * 4];
        float4 x2 = *(const float4*)&e1[q2 * 4];
        float4 x3 = *(const float4*)&e1[q3 * 4];
        const float* r0 = h1 + (size_t)s0 * 256;
        const float* r1 = h1 + (size_t)s1 * 256;
        const float* r2 = h1 + (size_t)s2 * 256;
        const float* r3 = h1 + (size_t)s3 * 256;
        float v00 = r0[lane], v01 = r0[lane + 64], v02 = r0[lane + 128], v03 = r0[lane + 192];
        float v10 = r1[lane], v11 = r1[lane + 64], v12 = r1[lane + 128], v13 = r1[lane + 192];
        float v20 = r2[lane], v21 = r2[lane + 64], v22 = r2[lane + 128], v23 = r2[lane + 192];
        float v30 = r3[lane], v31 = r3[lane + 64], v32 = r3[lane + 128], v33 = r3[lane + 192];
        a0 += v00 * (x0.x * i0) + v10 * (x1.x * i0) + v20 * (x2.x * i0) + v30 * (x3.x * i0);
        a1 += v01 * (x0.y * i1) + v11 * (x1.y * i1) + v21 * (x2.y * i1) + v31 * (x3.y * i1);
        a2 += v02 * (x0.z * i2) + v12 * (x1.z * i2) + v22 * (x2.z * i2) + v32 * (x3.z * i2);
        a3 += v03 * (x0.w * i3) + v13 * (x1.w * i3) + v23 * (x2.w * i3) + v33 * (x3.w * i3);
    }
    for (; i < end; ++i) {
        int s = esrc[i], e = eidx[i];
        float4 ex = *(const float4*)&e1[e * 4];
        const float* hr = h1 + (size_t)s * 256;
        a0 += hr[lane      ] * (ex.x * i0);
        a1 += hr[lane + 64 ] * (ex.y * i1);
        a2 += hr[lane + 128] * (ex.z * i2);
        a3 += hr[lane + 192] * (ex.w * i3);
    }
    float* orow = h1b + (size_t)d * 256;
    float v;
    v = a0 + b1[lane      ]; orow[lane      ] = v > 0.f ? v : expm1f(v);
    v = a1 + b1[lane + 64 ]; orow[lane + 64 ] = v > 0.f ? v : expm1f(v);
    v = a2 + b1[lane + 128]; orow[lane + 128] = v > 0.f ? v : expm1f(v);
    v = a3 + b1[lane + 192]; orow[lane + 192] = v > 0.f ? v : expm1f(v);
}

// ================= layer 2 =================
__global__ void k_proj2(const float* __restrict__ h, const float* __restrict__ W2,
                        const float* __restrict__ a_src, const float* __restrict__ a_dst,
                        float* __restrict__ h2, float* __restrict__ as2, float* __restrict__ ad2) {
    int n = blockIdx.x;
    int t = threadIdx.x;  // 0..63
    __shared__ float row[256];
    for (int k = t; k < 256; k += 64) row[k] = h[n * 256 + k];
    __syncthreads();
    float acc = 0.f;
#pragma unroll 8
    for (int k = 0; k < 256; ++k) acc += row[k] * W2[k * 64 + t];
    h2[n * 64 + t] = acc;
    float ps = acc * a_src[t];
    float pd = acc * a_dst[t];
    for (int off = 32; off > 0; off >>= 1) {
        ps += __shfl_down(ps, off);
        pd += __shfl_down(pd, off);
    }
    if (t == 0) { as2[n] = ps; ad2[n] = pd; }
}

__global__ void k_edge2(const int* __restrict__ ei, const float* __restrict__ as2,
                        const float* __restrict__ ad2, float* __restrict__ e2,
                        unsigned* __restrict__ m2) {
    int e = blockIdx.x * blockDim.x + threadIdx.x;
    if (e >= N_EDGES_TOT) return;
    int s, d; edge_sd(e, ei, s, d);
    float sc = as2[s] + ad2[d];
    sc = sc > 0.f ? sc : NEG_SLOPEF * sc;
    e2[e] = sc;
    atomicMax(&m2[d], fmap(sc));
}

__global__ void k_exp2(const int* __restrict__ ei, float* __restrict__ e2,
                       const unsigned* __restrict__ m2, float* __restrict__ denom2) {
    int e = blockIdx.x * blockDim.x + threadIdx.x;
    if (e >= N_EDGES_TOT) return;
    int s, d; edge_sd(e, ei, s, d);
    float ex = expf(e2[e] - funmap(m2[d]));
    e2[e] = ex;
    atomicAdd(&denom2[d], ex);
}

// CSR gather aggregation layer 2, one wave per dst, 4-edge unroll.
// Fused bias + ELU. Plain store to h2b (NO pool atomics — batch is sorted;
// per-graph reduction happens in k_pool2).
__global__ void k_aggr2(const int* __restrict__ rowptr, const int* __restrict__ esrc,
                        const int* __restrict__ eidx, const float* __restrict__ h2,
                        const float* __restrict__ e2, const float* __restrict__ denom2,
                        const float* __restrict__ b2, float* __restrict__ h2b) {
    int d = blockIdx.x * 4 + (threadIdx.x >> 6);
    if (d >= N_NODESC) return;
    int lane = threadIdx.x & 63;
    int beg = rowptr[d], end = rowptr[d + 1];
    float rinv = 1.f / denom2[d];
    float acc = 0.f;
    int i = beg;
    for (; i + 4 <= end; i += 4) {
        int s0 = esrc[i], s1 = esrc[i + 1], s2 = esrc[i + 2], s3 = esrc[i + 3];
        int q0 = eidx[i], q1 = eidx[i + 1], q2 = eidx[i + 2], q3 = eidx[i + 3];
        float w0 = e2[q0], w1 = e2[q1], w2 = e2[q2], w3 = e2[q3];
        float v0 = h2[(size_t)s0 * 64 + lane];
        float v1 = h2[(size_t)s1 * 64 + lane];
        float v2 = h2[(size_t)s2 * 64 + lane];
        float v3 = h2[(size_t)s3 * 64 + lane];
        acc += v0 * (w0 * rinv) + v1 * (w1 * rinv) + v2 * (w2 * rinv) + v3 * (w3 * rinv);
    }
    for (; i < end; ++i) {
        acc += h2[(size_t)esrc[i] * 64 + lane] * (e2[eidx[i]] * rinv);
    }
    float v = acc + b2[lane];
    v = v > 0.f ? v : expm1f(v);
    h2b[(size_t)d * 64 + lane] = v;
}

// Per-graph mean-pool pre-sum: batch is SORTED, so graph g owns a contiguous
// node range [lo, hi) found by binary search. 64 blocks x 1024 threads;
// 16 row-groups x 64 channels, coalesced reads, LDS reduce. No atomics.
__global__ void k_pool2(const float* __restrict__ h2b, const int* __restrict__ batch,
                        float* __restrict__ pool, float* __restrict__ cnt) {
    int g = blockIdx.x;            // 0..63
    int t = threadIdx.x;           // 0..1023
    int lane = t & 63, rg = t >> 6;  // 16 row groups
    int lo, hi;
    {
        int l = 0, r = N_NODESC;
        while (l < r) { int m = (l + r) >> 1; if (batch[m] < g) l = m + 1; else r = m; }
        lo = l;
        r = N_NODESC;
        while (l < r) { int m = (l + r) >> 1; if (batch[m] < g + 1) l = m + 1; else r = m; }
        hi = l;
    }
    float acc = 0.f;
    for (int n = lo + rg; n < hi; n += 16)
        acc += h2b[(size_t)n * 64 + lane];
    __shared__ float ps[16][64];
    ps[rg][lane] = acc;
    __syncthreads();
    if (t < 64) {
        float s = 0.f;
#pragma unroll
        for (int r = 0; r < 16; ++r) s += ps[r][t];
        pool[g * 64 + t] = s;
        if (t == 0) cnt[g] = (float)(hi - lo);
    }
}

// ---- GRU input-gate precompute: gi[step][j] = bih[j] + sum_k (pool[step][k]/cnt[step]) * Wih[j][k]
__global__ void k_gi(const float* __restrict__ pool, const float* __restrict__ cnt,
                     const float* __restrict__ Wih, const float* __restrict__ bih,
                     float* __restrict__ gi) {
    int idx = blockIdx.x * blockDim.x + threadIdx.x;
    if (idx >= NUM_GRAPHSC * 192) return;
    int step = idx / 192, j = idx % 192;
    float inv = 1.f / fmaxf(cnt[step], 1.0f);
    const float* w = Wih + j * 64;
    const float* p = pool + step * 64;
    float acc = bih[j];
#pragma unroll
    for (int k4 = 0; k4 < 16; ++k4) {
        float4 pv = *(const float4*)&p[k4 * 4];
        float4 wv = *(const float4*)&w[k4 * 4];
        acc += (pv.x * wv.x + pv.y * wv.y + pv.z * wv.z + pv.w * wv.w) * inv;
    }
    gi[step * 192 + j] = acc;
}

// ---- GRU serial half: ONE WAVE, zero barriers in the loop.
// Thread t holds Whh rows {t, 64+t, 128+t} in registers (192 VGPRs) and h[t]
// in a register. h@Whh.T via __shfl broadcast (compile-time lane -> readlane).
// gi staged once into LDS (stride-1 reads = conflict-free). Fused FC.
__global__ void __launch_bounds__(64, 1)
k_gru2(const float* __restrict__ gi, const float* __restrict__ Whh,
       const float* __restrict__ bhh, const float* __restrict__ Wfc,
       const float* __restrict__ bfc, float* __restrict__ out) {
    int t = threadIdx.x;  // 0..63
    __shared__ float gi_s[NUM_GRAPHSC * 192];   // 48 KB

    // stage gi -> LDS (single wave: float4, 48 iters/thread)
    for (int i = t; i < NUM_GRAPHSC * 192 / 4; i += 64) {
        ((float4*)gi_s)[i] = ((const float4*)gi)[i];
    }
    // preload all three gate rows of Whh into registers (static indexing)
    float wr[64], wz[64], wn[64];
#pragma unroll
    for (int k4 = 0; k4 < 16; ++k4) {
        float4 vr = *(const float4*)&Whh[(t      ) * 64 + k4 * 4];
        float4 vz = *(const float4*)&Whh[(t + 64 ) * 64 + k4 * 4];
        float4 vn = *(const float4*)&Whh[(t + 128) * 64 + k4 * 4];
        wr[k4*4+0] = vr.x; wr[k4*4+1] = vr.y; wr[k4*4+2] = vr.z; wr[k4*4+3] = vr.w;
        wz[k4*4+0] = vz.x; wz[k4*4+1] = vz.y; wz[k4*4+2] = vz.z; wz[k4*4+3] = vz.w;
        wn[k4*4+0] = vn.x; wn[k4*4+1] = vn.y; wn[k4*4+2] = vn.z; wn[k4*4+3] = vn.w;
    }
    float br_ = bhh[t], bz_ = bhh[64 + t], bn_ = bhh[128 + t];
    float wfc = Wfc[t];
    float bf  = bfc[0];
    float hreg = 0.f;

    for (int step = 0; step < NUM_GRAPHSC; ++step) {
        float ar = br_, az = bz_, an = bn_;
#pragma unroll
        for (int k = 0; k < 64; ++k) {
            float hk = __shfl(hreg, k);          // lane broadcast, no LDS
            ar += hk * wr[k];
            az += hk * wz[k];
            an += hk * wn[k];
        }
        const float* gs = &gi_s[step * 192];
        float r  = 1.f / (1.f + expf(-(gs[t]       + ar)));
        float z  = 1.f / (1.f + expf(-(gs[64 + t]  + az)));
        float nn = tanhf(gs[128 + t] + r * an);
        hreg = (1.f - z) * nn + z * hreg;
        // fused FC: out[step] = sum_t hreg*Wfc[t] + bfc
        float p = hreg * wfc;
        for (int off = 32; off > 0; off >>= 1) p += __shfl_down(p, off);
        if (t == 0) out[step] = p + bf;
    }
}

extern "C" void kernel_launch(void* const* d_in, const int* in_sizes, int n_in,
                              void* d_out, int out_size, void* d_ws, size_t ws_size,
                              hipStream_t stream) {
    const float* x      = (const float*)d_in[0];
    const int*   ei     = (const int*)d_in[1];   // [2, 320000]
    const int*   batch  = (const int*)d_in[2];
    const float* W1     = (const float*)d_in[3];
    const float* a_src1 = (const float*)d_in[4];
    const float* a_dst1 = (const float*)d_in[5];
    const float* b1     = (const float*)d_in[6];
    const float* W2     = (const float*)d_in[7];
    const float* a_src2 = (const float*)d_in[8];
    const float* a_dst2 = (const float*)d_in[9];
    const float* b2     = (const float*)d_in[10];
    const float* Wih    = (const float*)d_in[11];
    const float* Whh    = (const float*)d_in[12];
    const float* bih    = (const float*)d_in[13];
    const float* bhh    = (const float*)d_in[14];
    const float* Wfc    = (const float*)d_in[15];
    const float* bfc    = (const float*)d_in[16];
    float* out = (float*)d_out;

    char* ws = (char*)d_ws;
    size_t off = 0;
    auto alloc = [&](size_t bytes) -> void* {
        void* p = ws + off;
        off += (bytes + 255) & ~(size_t)255;
        return p;
    };
    float*    h1     = (float*)   alloc((size_t)N_NODESC * 256 * 4);
    float*    h1b    = (float*)   alloc((size_t)N_NODESC * 256 * 4);
    float*    as1    = (float*)   alloc((size_t)N_NODESC * HEADSC * 4);
    float*    ad1    = (float*)   alloc((size_t)N_NODESC * HEADSC * 4);
    float*    e1     = (float*)   alloc((size_t)N_EDGES_TOT * HEADSC * 4);
    unsigned* m1     = (unsigned*)alloc((size_t)N_NODESC * HEADSC * 4);
    float*    denom1 = (float*)   alloc((size_t)N_NODESC * HEADSC * 4);
    float*    h2     = (float*)   alloc((size_t)N_NODESC * 64 * 4);
    float*    h2b    = (float*)   alloc((size_t)N_NODESC * 64 * 4);
    float*    as2    = (float*)   alloc((size_t)N_NODESC * 4);
    float*    ad2    = (float*)   alloc((size_t)N_NODESC * 4);
    float*    e2     = (float*)   alloc((size_t)N_EDGES_TOT * 4);
    unsigned* m2     = (unsigned*)alloc((size_t)N_NODESC * 4);
    float*    denom2 = (float*)   alloc((size_t)N_NODESC * 4);
    float*    pool   = (float*)   alloc((size_t)NUM_GRAPHSC * 64 * 4);
    float*    cnt    = (float*)   alloc((size_t)NUM_GRAPHSC * 4);
    float*    gi     = (float*)   alloc((size_t)NUM_GRAPHSC * 192 * 4);
    int*      deg    = (int*)     alloc((size_t)N_NODESC * 4);
    int*      rowptr = (int*)     alloc((size_t)(N_NODESC + 1) * 4);
    int*      cursor = (int*)     alloc((size_t)N_NODESC * 4);
    int*      esrc   = (int*)     alloc((size_t)N_EDGES_TOT * 4);
    int*      eidx   = (int*)     alloc((size_t)N_EDGES_TOT * 4);

    // zero-init accumulators (ws is poisoned 0xAA before every call).
    // memset-0 on m1/m2 is a valid -inf under fmap.
    hipMemsetAsync(deg,    0, (size_t)N_NODESC * 4, stream);
    hipMemsetAsync(m1,     0, (size_t)N_NODESC * HEADSC * 4, stream);
    hipMemsetAsync(denom1, 0, (size_t)N_NODESC * HEADSC * 4, stream);
    hipMemsetAsync(m2,     0, (size_t)N_NODESC * 4, stream);
    hipMemsetAsync(denom2, 0, (size_t)N_NODESC * 4, stream);

    // ---- CSR build ----
    k_hist   <<<(N_EDGES_TOT + 255) / 256, 256, 0, stream>>>(ei, deg);
    k_scan   <<<1, 1024, 0, stream>>>(deg, rowptr, cursor);
    k_scatter<<<(N_EDGES_TOT + 255) / 256, 256, 0, stream>>>(ei, cursor, esrc, eidx);

    // ---- layer 1 ----
    k_proj1<<<N_NODESC, 256, 0, stream>>>(x, W1, a_src1, a_dst1, h1, as1, ad1);
    {
        int tot = N_EDGES_TOT * HEADSC;
        k_edge1<<<(tot + 255) / 256, 256, 0, stream>>>(ei, as1, ad1, e1, m1);
        k_exp1 <<<(tot + 255) / 256, 256, 0, stream>>>(ei, e1, m1, denom1);
    }
    k_aggr1<<<(N_NODESC + 3) / 4, 256, 0, stream>>>(rowptr, esrc, eidx, h1, e1, denom1, b1, h1b);

    // ---- layer 2 ----
    k_proj2<<<N_NODESC, 64, 0, stream>>>(h1b, W2, a_src2, a_dst2, h2, as2, ad2);
    k_edge2<<<(N_EDGES_TOT + 255) / 256, 256, 0, stream>>>(ei, as2, ad2, e2, m2);
    k_exp2 <<<(N_EDGES_TOT + 255) / 256, 256, 0, stream>>>(ei, e2, m2, denom2);
    k_aggr2<<<(N_NODESC + 3) / 4, 256, 0, stream>>>(rowptr, esrc, eidx, h2, e2, denom2, b2, h2b);

    // ---- pool (contiguous segment sum, no atomics) + GRU + FC ----
    k_pool2<<<NUM_GRAPHSC, 1024, 0, stream>>>(h2b, batch, pool, cnt);
    k_gi   <<<(NUM_GRAPHSC * 192 + 255) / 256, 256, 0, stream>>>(pool, cnt, Wih, bih, gi);
    k_gru2 <<<1, 64, 0, stream>>>(gi, Whh, bhh, Wfc, bfc, out);
}

// Round 15
// 436.458 us; speedup vs baseline: 1.1172x; 1.1172x over previous
//
#include <hip/hip_runtime.h>
#include <math.h>

#define N_NODESC    20000
#define N_EDGES_RAW 320000
#define N_EDGES_TOT 340000   // + self-loops
#define IN_CHC      4
#define HIDC        64
#define HEADSC      4
#define NUM_GRAPHSC 64
#define NEG_SLOPEF  0.2f

// ---- monotonic float<->uint mapping for atomic max (handles negatives) ----
__device__ __forceinline__ unsigned fmap(float f) {
    unsigned u = __float_as_uint(f);
    return (u & 0x80000000u) ? ~u : (u | 0x80000000u);
}
__device__ __forceinline__ float funmap(unsigned u) {
    u = (u & 0x80000000u) ? (u ^ 0x80000000u) : ~u;
    return __uint_as_float(u);
}

__device__ __forceinline__ void edge_sd(int e, const int* __restrict__ ei, int& s, int& d) {
    if (e < N_EDGES_RAW) { s = ei[e]; d = ei[N_EDGES_RAW + e]; }
    else                 { s = d = e - N_EDGES_RAW; }
}

// ================= CSR build (by destination) =================
__global__ void k_hist(const int* __restrict__ ei, int* __restrict__ deg) {
    int e = blockIdx.x * blockDim.x + threadIdx.x;
    if (e >= N_EDGES_TOT) return;
    int s, d; edge_sd(e, ei, s, d);
    atomicAdd(&deg[d], 1);
}

// single block, 1024 threads, 20 elems/thread: exclusive scan of deg -> rowptr, cursor
__global__ void k_scan(const int* __restrict__ deg, int* __restrict__ rowptr,
                       int* __restrict__ cursor) {
    const int PER = 20;
    int t = threadIdx.x;           // 0..1023
    int base = t * PER;
    int local[PER];
    int s = 0;
#pragma unroll
    for (int i = 0; i < PER; ++i) {
        int idx = base + i;
        int v = (idx < N_NODESC) ? deg[idx] : 0;
        local[i] = s; s += v;
    }
    int lane = t & 63, wid = t >> 6;
    int inc = s;
    for (int off = 1; off < 64; off <<= 1) {
        int u = __shfl_up(inc, off);
        if (lane >= off) inc += u;
    }
    __shared__ int wsum[16], woff[16];
    if (lane == 63) wsum[wid] = inc;
    __syncthreads();
    if (t == 0) { int a = 0; for (int w = 0; w < 16; ++w) { woff[w] = a; a += wsum[w]; } }
    __syncthreads();
    int thread_excl = inc - s + woff[wid];
#pragma unroll
    for (int i = 0; i < PER; ++i) {
        int idx = base + i;
        if (idx < N_NODESC) {
            int v = thread_excl + local[i];
            rowptr[idx] = v; cursor[idx] = v;
        }
    }
    if (t == 1023) rowptr[N_NODESC] = thread_excl + s;
}

__global__ void k_scatter(const int* __restrict__ ei, int* __restrict__ cursor,
                          int* __restrict__ esrc, int* __restrict__ eidx) {
    int e = blockIdx.x * blockDim.x + threadIdx.x;
    if (e >= N_EDGES_TOT) return;
    int s, d; edge_sd(e, ei, s, d);
    int pos = atomicAdd(&cursor[d], 1);
    esrc[pos] = s;
    eidx[pos] = e;
}

// ================= layer 1 =================
// grid = N_NODES blocks, 256 threads. h1[n][256], as1/ad1[n][4]
__global__ void k_proj1(const float* __restrict__ x, const float* __restrict__ W1,
                        const float* __restrict__ a_src, const float* __restrict__ a_dst,
                        float* __restrict__ h1, float* __restrict__ as1, float* __restrict__ ad1) {
    int n = blockIdx.x;
    int t = threadIdx.x;                 // 0..255 ; head = t>>6, c = t&63
    __shared__ float xs[IN_CHC];
    if (t < IN_CHC) xs[t] = x[n * IN_CHC + t];
    __syncthreads();
    float h = xs[0] * W1[t] + xs[1] * W1[256 + t] + xs[2] * W1[512 + t] + xs[3] * W1[768 + t];
    h1[n * 256 + t] = h;
    float ps = h * a_src[t];
    float pd = h * a_dst[t];
    for (int off = 32; off > 0; off >>= 1) {   // 64-lane wave == one head
        ps += __shfl_down(ps, off);
        pd += __shfl_down(pd, off);
    }
    if ((t & 63) == 0) {
        int head = t >> 6;
        as1[n * HEADSC + head] = ps;
        ad1[n * HEADSC + head] = pd;
    }
}

__global__ void k_edge1(const int* __restrict__ ei, const float* __restrict__ as1,
                        const float* __restrict__ ad1, float* __restrict__ e1,
                        unsigned* __restrict__ m1) {
    int idx = blockIdx.x * blockDim.x + threadIdx.x;
    if (idx >= N_EDGES_TOT * HEADSC) return;
    int e = idx >> 2, hd = idx & 3;
    int s, d; edge_sd(e, ei, s, d);
    float sc = as1[s * HEADSC + hd] + ad1[d * HEADSC + hd];
    sc = sc > 0.f ? sc : NEG_SLOPEF * sc;
    e1[idx] = sc;
    atomicMax(&m1[d * HEADSC + hd], fmap(sc));
}

__global__ void k_exp1(const int* __restrict__ ei, float* __restrict__ e1,
                       const unsigned* __restrict__ m1, float* __restrict__ denom1) {
    int idx = blockIdx.x * blockDim.x + threadIdx.x;
    if (idx >= N_EDGES_TOT * HEADSC) return;
    int e = idx >> 2, hd = idx & 3;
    int s, d; edge_sd(e, ei, s, d);
    float ex = expf(e1[idx] - funmap(m1[d * HEADSC + hd]));
    e1[idx] = ex;
    atomicAdd(&denom1[d * HEADSC + hd], ex);
}

// CSR gather aggregation, one wave per dst, 4-edge unroll for MLP.
// Fused bias + ELU. grid = ceil(N/4) blocks x 256 threads (4 waves).
__global__ void k_aggr1(const int* __restrict__ rowptr, const int* __restrict__ esrc,
                        const int* __restrict__ eidx, const float* __restrict__ h1,
                        const float* __restrict__ e1, const float* __restrict__ denom1,
                        const float* __restrict__ b1, float* __restrict__ h1b) {
    int d = blockIdx.x * 4 + (threadIdx.x >> 6);
    if (d >= N_NODESC) return;
    int lane = threadIdx.x & 63;
    int beg = rowptr[d], end = rowptr[d + 1];
    float4 den = *(const float4*)&denom1[d * 4];
    float i0 = 1.f / den.x, i1 = 1.f / den.y, i2 = 1.f / den.z, i3 = 1.f / den.w;
    float a0 = 0.f, a1 = 0.f, a2 = 0.f, a3 = 0.f;
    int i = beg;
    for (; i + 4 <= end; i += 4) {
        int s0 = esrc[i], s1 = esrc[i + 1], s2 = esrc[i + 2], s3 = esrc[i + 3];
        int q0 = eidx[i], q1 = eidx[i + 1], q2 = eidx[i + 2], q3 = eidx[i + 3];
        float4 x0 = *(const float4*)&e1[q0 * 4];
        float4 x1 = *(const float4*)&e1[q1 * 4];
        float4 x2 = *(const float4*)&e1[q2 * 4];
        float4 x3 = *(const float4*)&e1[q3 * 4];
        const float* r0 = h1 + (size_t)s0 * 256;
        const float* r1 = h1 + (size_t)s1 * 256;
        const float* r2 = h1 + (size_t)s2 * 256;
        const float* r3 = h1 + (size_t)s3 * 256;
        float v00 = r0[lane], v01 = r0[lane + 64], v02 = r0[lane + 128], v03 = r0[lane + 192];
        float v10 = r1[lane], v11 = r1[lane + 64], v12 = r1[lane + 128], v13 = r1[lane + 192];
        float v20 = r2[lane], v21 = r2[lane + 64], v22 = r2[lane + 128], v23 = r2[lane + 192];
        float v30 = r3[lane], v31 = r3[lane + 64], v32 = r3[lane + 128], v33 = r3[lane + 192];
        a0 += v00 * (x0.x * i0) + v10 * (x1.x * i0) + v20 * (x2.x * i0) + v30 * (x3.x * i0);
        a1 += v01 * (x0.y * i1) + v11 * (x1.y * i1) + v21 * (x2.y * i1) + v31 * (x3.y * i1);
        a2 += v02 * (x0.z * i2) + v12 * (x1.z * i2) + v22 * (x2.z * i2) + v32 * (x3.z * i2);
        a3 += v03 * (x0.w * i3) + v13 * (x1.w * i3) + v23 * (x2.w * i3) + v33 * (x3.w * i3);
    }
    for (; i < end; ++i) {
        int s = esrc[i], e = eidx[i];
        float4 ex = *(const float4*)&e1[e * 4];
        const float* hr = h1 + (size_t)s * 256;
        a0 += hr[lane      ] * (ex.x * i0);
        a1 += hr[lane + 64 ] * (ex.y * i1);
        a2 += hr[lane + 128] * (ex.z * i2);
        a3 += hr[lane + 192] * (ex.w * i3);
    }
    float* orow = h1b + (size_t)d * 256;
    float v;
    v = a0 + b1[lane      ]; orow[lane      ] = v > 0.f ? v : expm1f(v);
    v = a1 + b1[lane + 64 ]; orow[lane + 64 ] = v > 0.f ? v : expm1f(v);
    v = a2 + b1[lane + 128]; orow[lane + 128] = v > 0.f ? v : expm1f(v);
    v = a3 + b1[lane + 192]; orow[lane + 192] = v > 0.f ? v : expm1f(v);
}

// ================= layer 2 =================
__global__ void k_proj2(const float* __restrict__ h, const float* __restrict__ W2,
                        const float* __restrict__ a_src, const float* __restrict__ a_dst,
                        float* __restrict__ h2, float* __restrict__ as2, float* __restrict__ ad2) {
    int n = blockIdx.x;
    int t = threadIdx.x;  // 0..63
    __shared__ float row[256];
    for (int k = t; k < 256; k += 64) row[k] = h[n * 256 + k];
    __syncthreads();
    float acc = 0.f;
#pragma unroll 8
    for (int k = 0; k < 256; ++k) acc += row[k] * W2[k * 64 + t];
    h2[n * 64 + t] = acc;
    float ps = acc * a_src[t];
    float pd = acc * a_dst[t];
    for (int off = 32; off > 0; off >>= 1) {
        ps += __shfl_down(ps, off);
        pd += __shfl_down(pd, off);
    }
    if (t == 0) { as2[n] = ps; ad2[n] = pd; }
}

__global__ void k_edge2(const int* __restrict__ ei, const float* __restrict__ as2,
                        const float* __restrict__ ad2, float* __restrict__ e2,
                        unsigned* __restrict__ m2) {
    int e = blockIdx.x * blockDim.x + threadIdx.x;
    if (e >= N_EDGES_TOT) return;
    int s, d; edge_sd(e, ei, s, d);
    float sc = as2[s] + ad2[d];
    sc = sc > 0.f ? sc : NEG_SLOPEF * sc;
    e2[e] = sc;
    atomicMax(&m2[d], fmap(sc));
}

__global__ void k_exp2(const int* __restrict__ ei, float* __restrict__ e2,
                       const unsigned* __restrict__ m2, float* __restrict__ denom2) {
    int e = blockIdx.x * blockDim.x + threadIdx.x;
    if (e >= N_EDGES_TOT) return;
    int s, d; edge_sd(e, ei, s, d);
    float ex = expf(e2[e] - funmap(m2[d]));
    e2[e] = ex;
    atomicAdd(&denom2[d], ex);
}

// CSR gather aggregation layer 2, one wave per dst, 4-edge unroll.
// Fused bias + ELU. Plain store to h2b (NO pool atomics — batch is sorted;
// per-graph reduction happens in k_pool2).
__global__ void k_aggr2(const int* __restrict__ rowptr, const int* __restrict__ esrc,
                        const int* __restrict__ eidx, const float* __restrict__ h2,
                        const float* __restrict__ e2, const float* __restrict__ denom2,
                        const float* __restrict__ b2, float* __restrict__ h2b) {
    int d = blockIdx.x * 4 + (threadIdx.x >> 6);
    if (d >= N_NODESC) return;
    int lane = threadIdx.x & 63;
    int beg = rowptr[d], end = rowptr[d + 1];
    float rinv = 1.f / denom2[d];
    float acc = 0.f;
    int i = beg;
    for (; i + 4 <= end; i += 4) {
        int s0 = esrc[i], s1 = esrc[i + 1], s2 = esrc[i + 2], s3 = esrc[i + 3];
        int q0 = eidx[i], q1 = eidx[i + 1], q2 = eidx[i + 2], q3 = eidx[i + 3];
        float w0 = e2[q0], w1 = e2[q1], w2 = e2[q2], w3 = e2[q3];
        float v0 = h2[(size_t)s0 * 64 + lane];
        float v1 = h2[(size_t)s1 * 64 + lane];
        float v2 = h2[(size_t)s2 * 64 + lane];
        float v3 = h2[(size_t)s3 * 64 + lane];
        acc += v0 * (w0 * rinv) + v1 * (w1 * rinv) + v2 * (w2 * rinv) + v3 * (w3 * rinv);
    }
    for (; i < end; ++i) {
        acc += h2[(size_t)esrc[i] * 64 + lane] * (e2[eidx[i]] * rinv);
    }
    float v = acc + b2[lane];
    v = v > 0.f ? v : expm1f(v);
    h2b[(size_t)d * 64 + lane] = v;
}

// Per-graph mean-pool pre-sum: batch is SORTED, so graph g owns a contiguous
// node range [lo, hi) found by binary search. 64 blocks x 1024 threads;
// 16 row-groups x 64 channels, coalesced reads, LDS reduce. No atomics.
__global__ void k_pool2(const float* __restrict__ h2b, const int* __restrict__ batch,
                        float* __restrict__ pool, float* __restrict__ cnt) {
    int g = blockIdx.x;            // 0..63
    int t = threadIdx.x;           // 0..1023
    int lane = t & 63, rg = t >> 6;  // 16 row groups
    int lo, hi;
    {
        int l = 0, r = N_NODESC;
        while (l < r) { int m = (l + r) >> 1; if (batch[m] < g) l = m + 1; else r = m; }
        lo = l;
        r = N_NODESC;
        while (l < r) { int m = (l + r) >> 1; if (batch[m] < g + 1) l = m + 1; else r = m; }
        hi = l;
    }
    float acc = 0.f;
    for (int n = lo + rg; n < hi; n += 16)
        acc += h2b[(size_t)n * 64 + lane];
    __shared__ float ps[16][64];
    ps[rg][lane] = acc;
    __syncthreads();
    if (t < 64) {
        float s = 0.f;
#pragma unroll
        for (int r = 0; r < 16; ++r) s += ps[r][t];
        pool[g * 64 + t] = s;
        if (t == 0) cnt[g] = (float)(hi - lo);
    }
}

// ---- GRU input-gate precompute: gi[step][j] = bih[j] + sum_k (pool[step][k]/cnt[step]) * Wih[j][k]
__global__ void k_gi(const float* __restrict__ pool, const float* __restrict__ cnt,
                     const float* __restrict__ Wih, const float* __restrict__ bih,
                     float* __restrict__ gi) {
    int idx = blockIdx.x * blockDim.x + threadIdx.x;
    if (idx >= NUM_GRAPHSC * 192) return;
    int step = idx / 192, j = idx % 192;
    float inv = 1.f / fmaxf(cnt[step], 1.0f);
    const float* w = Wih + j * 64;
    const float* p = pool + step * 64;
    float acc = bih[j];
#pragma unroll
    for (int k4 = 0; k4 < 16; ++k4) {
        float4 pv = *(const float4*)&p[k4 * 4];
        float4 wv = *(const float4*)&w[k4 * 4];
        acc += (pv.x * wv.x + pv.y * wv.y + pv.z * wv.z + pv.w * wv.w) * inv;
    }
    gi[step * 192 + j] = acc;
}

// ---- GRU serial half, 192 threads. Weight row t held in 16 NAMED float4
// registers (no arrays -> compiler cannot demote to scratch; rule #20).
// h read as 16 uniform float4 LDS loads (broadcast). 4 independent partial
// sums cut the dependent-FMA chain 256 -> ~70 cycles.
#define LDW(i) float4 w##i = wp[i];
#define LDH(i) float4 h##i = hp[i];
#define D4(a, b) (a.x * b.x + a.y * b.y + a.z * b.z + a.w * b.w)
__global__ void __launch_bounds__(192)
k_gru2(const float* __restrict__ gi, const float* __restrict__ Whh,
       const float* __restrict__ bhh, const float* __restrict__ Wfc,
       const float* __restrict__ bfc, float* __restrict__ out) {
    int t = threadIdx.x;  // 0..191
    __shared__ float gi_s[NUM_GRAPHSC * 192];   // 48 KB
    __shared__ float h[64];
    __shared__ float g[192];

    // stage gi -> LDS (coalesced float4)
    for (int i = t; i < NUM_GRAPHSC * 192 / 4; i += 192) {
        ((float4*)gi_s)[i] = ((const float4*)gi)[i];
    }
    const float4* wp = (const float4*)(Whh + (size_t)t * 64);
    LDW(0)  LDW(1)  LDW(2)  LDW(3)  LDW(4)  LDW(5)  LDW(6)  LDW(7)
    LDW(8)  LDW(9)  LDW(10) LDW(11) LDW(12) LDW(13) LDW(14) LDW(15)
    float bh  = bhh[t];
    float wfc = (t < 64) ? Wfc[t] : 0.f;
    float bf  = bfc[0];
    if (t < 64) h[t] = 0.f;
    __syncthreads();

    for (int step = 0; step < NUM_GRAPHSC; ++step) {
        const float4* hp = (const float4*)h;   // uniform address -> broadcast reads
        LDH(0)  LDH(1)  LDH(2)  LDH(3)  LDH(4)  LDH(5)  LDH(6)  LDH(7)
        LDH(8)  LDH(9)  LDH(10) LDH(11) LDH(12) LDH(13) LDH(14) LDH(15)
        float p0 = D4(h0, w0)  + D4(h4, w4)  + D4(h8,  w8)  + D4(h12, w12);
        float p1 = D4(h1, w1)  + D4(h5, w5)  + D4(h9,  w9)  + D4(h13, w13);
        float p2 = D4(h2, w2)  + D4(h6, w6)  + D4(h10, w10) + D4(h14, w14);
        float p3 = D4(h3, w3)  + D4(h7, w7)  + D4(h11, w11) + D4(h15, w15);
        g[t] = bh + ((p0 + p1) + (p2 + p3));
        __syncthreads();
        if (t < 64) {
            const float* gs = &gi_s[step * 192];
            float r  = 1.f / (1.f + expf(-(gs[t]       + g[t])));
            float z  = 1.f / (1.f + expf(-(gs[64 + t]  + g[64 + t])));
            float nn = tanhf(gs[128 + t] + r * g[128 + t]);
            float hn = (1.f - z) * nn + z * h[t];
            h[t] = hn;
            float p = hn * wfc;
            for (int off = 32; off > 0; off >>= 1) p += __shfl_down(p, off);
            if (t == 0) out[step] = p + bf;
        }
        __syncthreads();
    }
}

extern "C" void kernel_launch(void* const* d_in, const int* in_sizes, int n_in,
                              void* d_out, int out_size, void* d_ws, size_t ws_size,
                              hipStream_t stream) {
    const float* x      = (const float*)d_in[0];
    const int*   ei     = (const int*)d_in[1];   // [2, 320000]
    const int*   batch  = (const int*)d_in[2];
    const float* W1     = (const float*)d_in[3];
    const float* a_src1 = (const float*)d_in[4];
    const float* a_dst1 = (const float*)d_in[5];
    const float* b1     = (const float*)d_in[6];
    const float* W2     = (const float*)d_in[7];
    const float* a_src2 = (const float*)d_in[8];
    const float* a_dst2 = (const float*)d_in[9];
    const float* b2     = (const float*)d_in[10];
    const float* Wih    = (const float*)d_in[11];
    const float* Whh    = (const float*)d_in[12];
    const float* bih    = (const float*)d_in[13];
    const float* bhh    = (const float*)d_in[14];
    const float* Wfc    = (const float*)d_in[15];
    const float* bfc    = (const float*)d_in[16];
    float* out = (float*)d_out;

    char* ws = (char*)d_ws;
    size_t off = 0;
    auto alloc = [&](size_t bytes) -> void* {
        void* p = ws + off;
        off += (bytes + 255) & ~(size_t)255;
        return p;
    };
    float*    h1     = (float*)   alloc((size_t)N_NODESC * 256 * 4);
    float*    h1b    = (float*)   alloc((size_t)N_NODESC * 256 * 4);
    float*    as1    = (float*)   alloc((size_t)N_NODESC * HEADSC * 4);
    float*    ad1    = (float*)   alloc((size_t)N_NODESC * HEADSC * 4);
    float*    e1     = (float*)   alloc((size_t)N_EDGES_TOT * HEADSC * 4);
    unsigned* m1     = (unsigned*)alloc((size_t)N_NODESC * HEADSC * 4);
    float*    denom1 = (float*)   alloc((size_t)N_NODESC * HEADSC * 4);
    float*    h2     = (float*)   alloc((size_t)N_NODESC * 64 * 4);
    float*    h2b    = (float*)   alloc((size_t)N_NODESC * 64 * 4);
    float*    as2    = (float*)   alloc((size_t)N_NODESC * 4);
    float*    ad2    = (float*)   alloc((size_t)N_NODESC * 4);
    float*    e2     = (float*)   alloc((size_t)N_EDGES_TOT * 4);
    unsigned* m2     = (unsigned*)alloc((size_t)N_NODESC * 4);
    float*    denom2 = (float*)   alloc((size_t)N_NODESC * 4);
    float*    pool   = (float*)   alloc((size_t)NUM_GRAPHSC * 64 * 4);
    float*    cnt    = (float*)   alloc((size_t)NUM_GRAPHSC * 4);
    float*    gi     = (float*)   alloc((size_t)NUM_GRAPHSC * 192 * 4);
    int*      deg    = (int*)     alloc((size_t)N_NODESC * 4);
    int*      rowptr = (int*)     alloc((size_t)(N_NODESC + 1) * 4);
    int*      cursor = (int*)     alloc((size_t)N_NODESC * 4);
    int*      esrc   = (int*)     alloc((size_t)N_EDGES_TOT * 4);
    int*      eidx   = (int*)     alloc((size_t)N_EDGES_TOT * 4);

    // zero-init accumulators (ws is poisoned 0xAA before every call).
    // memset-0 on m1/m2 is a valid -inf under fmap.
    hipMemsetAsync(deg,    0, (size_t)N_NODESC * 4, stream);
    hipMemsetAsync(m1,     0, (size_t)N_NODESC * HEADSC * 4, stream);
    hipMemsetAsync(denom1, 0, (size_t)N_NODESC * HEADSC * 4, stream);
    hipMemsetAsync(m2,     0, (size_t)N_NODESC * 4, stream);
    hipMemsetAsync(denom2, 0, (size_t)N_NODESC * 4, stream);

    // ---- CSR build ----
    k_hist   <<<(N_EDGES_TOT + 255) / 256, 256, 0, stream>>>(ei, deg);
    k_scan   <<<1, 1024, 0, stream>>>(deg, rowptr, cursor);
    k_scatter<<<(N_EDGES_TOT + 255) / 256, 256, 0, stream>>>(ei, cursor, esrc, eidx);

    // ---- layer 1 ----
    k_proj1<<<N_NODESC, 256, 0, stream>>>(x, W1, a_src1, a_dst1, h1, as1, ad1);
    {
        int tot = N_EDGES_TOT * HEADSC;
        k_edge1<<<(tot + 255) / 256, 256, 0, stream>>>(ei, as1, ad1, e1, m1);
        k_exp1 <<<(tot + 255) / 256, 256, 0, stream>>>(ei, e1, m1, denom1);
    }
    k_aggr1<<<(N_NODESC + 3) / 4, 256, 0, stream>>>(rowptr, esrc, eidx, h1, e1, denom1, b1, h1b);

    // ---- layer 2 ----
    k_proj2<<<N_NODESC, 64, 0, stream>>>(h1b, W2, a_src2, a_dst2, h2, as2, ad2);
    k_edge2<<<(N_EDGES_TOT + 255) / 256, 256, 0, stream>>>(ei, as2, ad2, e2, m2);
    k_exp2 <<<(N_EDGES_TOT + 255) / 256, 256, 0, stream>>>(ei, e2, m2, denom2);
    k_aggr2<<<(N_NODESC + 3) / 4, 256, 0, stream>>>(rowptr, esrc, eidx, h2, e2, denom2, b2, h2b);

    // ---- pool (contiguous segment sum, no atomics) + GRU + FC ----
    k_pool2<<<NUM_GRAPHSC, 1024, 0, stream>>>(h2b, batch, pool, cnt);
    k_gi   <<<(NUM_GRAPHSC * 192 + 255) / 256, 256, 0, stream>>>(pool, cnt, Wih, bih, gi);
    k_gru2 <<<1, 192, 0, stream>>>(gi, Whh, bhh, Wfc, bfc, out);
}